// Round 7
// baseline (247.166 us; speedup 1.0000x reference)
//
#include <hip/hip_runtime.h>

// ---------- problem constants ----------
#define BB   4096   // batch
#define IN_  256
#define NN   128
#define KK   4
#define JJ   64
#define NG   512        // N*K
#define WS_  131072     // IN*NG
#define PER  131584     // WS_+NG
#define TP   263168     // 2*PER
#define OUTD 128

typedef __attribute__((ext_vector_type(8))) short short8;
typedef __attribute__((ext_vector_type(4))) float f32x4;

#define VW(N) asm volatile("s_waitcnt vmcnt(" #N ")" ::: "memory")

__device__ __forceinline__ unsigned short f2bf(float f){
  unsigned u = __float_as_uint(f);
  return (unsigned short)((u + 0x7fffu + ((u >> 16) & 1u)) >> 16);
}

__device__ __forceinline__ void gload16(const void* g, void* l){
  __builtin_amdgcn_global_load_lds((const __attribute__((address_space(1))) void*)g,
                                   (__attribute__((address_space(3))) void*)l, 16, 0, 0);
}

// ---------- 1. f32 -> bf16 convert: x, Wb0, Wb1 ----------
#define XE  (4096u*256u)            // 1048576
#define W0E (XE + 8388608u)         // + 128*4*64*256
#define W1E (W0E + 4194304u)        // + 128*4*64*128

__global__ void k_convert(const float* __restrict__ x,
                          const float* __restrict__ w0,
                          const float* __restrict__ w1,
                          unsigned short* __restrict__ xb,
                          unsigned short* __restrict__ w0b,
                          unsigned short* __restrict__ w1b){
  size_t i = ((size_t)blockIdx.x*256 + threadIdx.x)*4;
  if (i >= W1E) return;
  const float* s; unsigned short* d; size_t off;
  if (i < XE)       { s = x;  d = xb;  off = i; }
  else if (i < W0E) { s = w0; d = w0b; off = i - XE; }
  else              { s = w1; d = w1b; off = i - W0E; }
  float4 v = *(const float4*)(s + off);
  ushort4 o;
  o.x = f2bf(v.x); o.y = f2bf(v.y); o.z = f2bf(v.z); o.w = f2bf(v.w);
  *(ushort4*)(d + off) = o;
}

// ---------- 2. hypernet MLP (context -> hv2[64]) ----------
__global__ void k_hyper(const float* __restrict__ ctx,
                        const float* __restrict__ h1w, const float* __restrict__ h1b,
                        const float* __restrict__ h2w, const float* __restrict__ h2b,
                        float* __restrict__ hv2){
  __shared__ float s1[32];
  int t = threadIdx.x;
  if (t < 32){
    float a = h1b[t];
    #pragma unroll 8
    for (int i = 0; i < 64; ++i) a += ctx[i]*h1w[t*64+i];
    s1[t] = fmaxf(a, 0.f);
  }
  __syncthreads();
  float a = h2b[t];
  #pragma unroll 8
  for (int i = 0; i < 32; ++i) a += s1[i]*h2w[t*32+i];
  hv2[t] = fmaxf(a, 0.f);
}

// ---------- 3. gw = hv2 @ h3w.T + h3b  ->  Wg_bf (1024x256 bf16), bg (1024 f32) ----------
__global__ void k_gw(const float* __restrict__ hv2,
                     const float* __restrict__ h3w, const float* __restrict__ h3b,
                     unsigned short* __restrict__ Wg_bf, float* __restrict__ bg){
  int t = threadIdx.x;
  int r = blockIdx.x*64 + (t >> 2);
  int q = t & 3;
  const float4* row = (const float4*)(h3w + (size_t)r*64);
  float a = 0.f;
  #pragma unroll
  for (int i = 0; i < 4; ++i){
    float4 v = row[q*4 + i];
    float4 h = *(const float4*)(hv2 + q*16 + i*4);
    a += v.x*h.x + v.y*h.y + v.z*h.z + v.w*h.w;
  }
  a += __shfl_xor(a, 1);
  a += __shfl_xor(a, 2);
  if (q == 0){
    a += h3b[r];
    if (r < WS_)          Wg_bf[r] = f2bf(a);
    else if (r < PER)     bg[r - WS_] = a;
    else if (r < PER+WS_) Wg_bf[WS_ + (r - PER)] = f2bf(a);
    else                  bg[512 + (r - (PER+WS_))] = a;
  }
}

// ---------- 4. gates GEMM: G_T[m(1024)][b(4096)] = sigmoid(Wg[m]·x[b] + bg[m]) ----------
__global__ __launch_bounds__(512, 1)
void k_gates(const unsigned short* __restrict__ Wg_bf,  // 1024 x 256
             const unsigned short* __restrict__ x_bf,   // 4096 x 256
             const float* __restrict__ bg,              // 1024
             float* __restrict__ GT){                    // 1024 x 4096
  __shared__ __align__(16) unsigned short As[128*64];
  __shared__ __align__(16) unsigned short Bs[256*64];
  const int tid  = threadIdx.x;
  const int lane = tid & 63;
  const int wid  = tid >> 6;
  const int wm = wid >> 2, wn = wid & 3;
  const int lrow = lane & 15, lk = lane >> 4;
  const int m0 = blockIdx.x*128;
  const int b0 = blockIdx.y*256;

  f32x4 zero = {0.f,0.f,0.f,0.f};
  f32x4 acc[4][4];
  #pragma unroll
  for (int i=0;i<4;++i)
    #pragma unroll
    for (int j=0;j<4;++j) acc[i][j] = zero;

  for (int kt = 0; kt < 256/64; ++kt){
    __syncthreads();
    #pragma unroll
    for (int i = 0; i < 2; ++i){
      int c = tid + i*512;
      int row = c >> 3, k8 = c & 7;
      uint4 v = *(const uint4*)(Wg_bf + (size_t)(m0+row)*256 + kt*64 + k8*8);
      int idx = (row*64 + k8*8) ^ ((row & 7) << 3);
      *(uint4*)(&As[idx]) = v;
    }
    #pragma unroll
    for (int i = 0; i < 4; ++i){
      int c = tid + i*512;
      int row = c >> 3, k8 = c & 7;
      uint4 v = *(const uint4*)(x_bf + (size_t)(b0+row)*256 + kt*64 + k8*8);
      int idx = (row*64 + k8*8) ^ ((row & 7) << 3);
      *(uint4*)(&Bs[idx]) = v;
    }
    __syncthreads();
    #pragma unroll
    for (int kk = 0; kk < 2; ++kk){
      short8 a[4], b[4];
      #pragma unroll
      for (int fm = 0; fm < 4; ++fm){
        int m = wm*64 + fm*16 + lrow;
        int idx = (m*64 + kk*32 + lk*8) ^ ((m & 7) << 3);
        a[fm] = *(const short8*)(&As[idx]);
      }
      #pragma unroll
      for (int fn = 0; fn < 4; ++fn){
        int r = wn*64 + fn*16 + lrow;
        int idx = (r*64 + kk*32 + lk*8) ^ ((r & 7) << 3);
        b[fn] = *(const short8*)(&Bs[idx]);
      }
      #pragma unroll
      for (int fm = 0; fm < 4; ++fm)
        #pragma unroll
        for (int fn = 0; fn < 4; ++fn)
          acc[fm][fn] = __builtin_amdgcn_mfma_f32_16x16x32_bf16(a[fm], b[fn], acc[fm][fn], 0, 0, 0);
    }
  }
  #pragma unroll
  for (int fm = 0; fm < 4; ++fm){
    float4 bgv = *(const float4*)(bg + m0 + wm*64 + fm*16 + lk*4);
    float bga[4] = {bgv.x, bgv.y, bgv.z, bgv.w};
    #pragma unroll
    for (int reg = 0; reg < 4; ++reg){
      int m = m0 + wm*64 + fm*16 + lk*4 + reg;
      #pragma unroll
      for (int fn = 0; fn < 4; ++fn){
        int b = b0 + wn*64 + fn*16 + lrow;
        float z = acc[fm][fn][reg] + bga[reg];
        GT[(size_t)m*4096 + b] = 1.f/(1.f + __expf(-z));
      }
    }
  }
}

// ---------- 5/6. fused DANN layer (A-frags in regs + 3-deep B pipeline) ----------
// A depends only on kt (not n): extract all A-fragments to registers once
// (128 VGPR for L0), then the loop touches LDS only for B: 64KB read + 32KB
// write per iter (was 160KB). B is 3-deep: stage(gi+2) issued at iter gi.
// LDS 128KB: B0|B1|B2 at shorts 0/16384/32768; A staged at ABASE (L0: 32768,
// aliasing B2 -- A is fully extracted to regs before B2's first write; L1:
// 49152, disjoint). Misc (GT/bb/Ws) loads moved to the epi iteration.
// Deterministic vmcnt counts (fences pin VMEM order):
//  L0 steady per kt {20,20,4,4}; gi=0,1 -> 4; gi=63 -> 0.
//  L1 steady {20,20}; gi=0,1 -> 4; gi=31 -> 16.
template<int KIN, int LAYER>
__global__ __launch_bounds__(512, 1)
void k_layer(const unsigned short* __restrict__ Abf,  // (4096, KIN) bf16
             const unsigned short* __restrict__ Wbf,  // (32768, KIN) bf16
             const float* __restrict__ bb,            // 32768
             const float* __restrict__ Ws,            // 128*256
             const float* __restrict__ GT,            // 1024 x 4096
             float* __restrict__ partg){              // [4][128][4096] f32
  constexpr int NT    = KIN/64;
  constexpr int ABASE = (NT == 4) ? 32768 : 49152;   // shorts
  __shared__ __align__(16) unsigned short lds[65536]; // 128 KB

  const int tid  = threadIdx.x;
  const int lane = tid & 63;
  const int wid  = tid >> 6;
  const int wm = wid >> 2, wn = wid & 3;
  const int lrow = lane & 15, lk = lane >> 4;

  const int id     = blockIdx.x;
  const int nstart = (id & 7) * 16;          // XCD-affine 16-n slice
  const int bbase  = (id >> 3) << 7;         // 32 bgroups * 128

  f32x4 zero = {0.f,0.f,0.f,0.f};
  f32x4 acc[4][4];
  #pragma unroll
  for (int i=0;i<4;++i)
    #pragma unroll
    for (int jj=0;jj<4;++jj) acc[i][jj] = zero;

  auto STAGE_B = [&](int sb, int n, int kt){
    #pragma unroll
    for (int i = 0; i < 4; ++i){
      int c = i*512 + tid;
      int row = c >> 3, kc = c & 7;
      const unsigned short* s = Wbf + (size_t)((n<<8)+row)*KIN + kt*64 + ((kc ^ (row&7))<<3);
      gload16(s, &lds[sb*16384 + (i*512 + wid*64)*8]);
    }
  };

  // prologue: stage A (all NT tiles), then B0, B1
  #pragma unroll
  for (int kt = 0; kt < NT; ++kt)
    #pragma unroll
    for (int i = 0; i < 2; ++i){
      int c = i*512 + tid;
      int row = c >> 3, kc = c & 7;
      const unsigned short* s = Abf + (size_t)(bbase+row)*KIN + kt*64 + ((kc ^ (row&7))<<3);
      gload16(s, &lds[ABASE + kt*8192 + (i*512 + wid*64)*8]);
    }
  STAGE_B(0, nstart, 0);
  STAGE_B(1, nstart, 1);
  asm volatile("" ::: "memory");
  VW(8);                                    // A landed (B0,B1 = 8 younger)
  __builtin_amdgcn_s_barrier();

  // extract all A-fragments to registers (static indices -> stays in VGPRs)
  short8 areg[NT][2][4];
  #pragma unroll
  for (int kt = 0; kt < NT; ++kt)
    #pragma unroll
    for (int kk = 0; kk < 2; ++kk)
      #pragma unroll
      for (int fm = 0; fm < 4; ++fm){
        int m = wm*64 + fm*16 + lrow;
        int idx = ABASE + kt*8192 + ((m*64 + kk*32 + lk*8) ^ ((m & 7) << 3));
        areg[kt][kk][fm] = *(const short8*)(&lds[idx]);
      }
  asm volatile("s_waitcnt lgkmcnt(0)" ::: "memory");
  __builtin_amdgcn_s_barrier();             // all waves done reading A region

  int cbuf = 0, sbuf = 2;
  #pragma unroll 1
  for (int nn = 0; nn < 16; ++nn){
    const int n = nstart + nn;
    #pragma unroll
    for (int kt = 0; kt < NT; ++kt){
      const bool epi = (kt == NT-1);

      // drain stage(gi) with exact younger-op counts
      if (NT == 4){
        if (kt == 0){ if (nn == 0) VW(4); else VW(20); }
        else if (kt == 1){ if (nn == 0) VW(4); else VW(20); }
        else if (kt == 2){ VW(4); }
        else { if (nn == 15) VW(0); else VW(4); }
      } else {
        if (kt == 0){ if (nn == 0) VW(4); else VW(20); }
        else { if (nn == 0) VW(4); else if (nn == 15) VW(16); else VW(20); }
      }
      __builtin_amdgcn_s_barrier();          // publish Bs[cbuf]

      // prefetch gi+2 (buffer safe: it was fully read at iter gi-1)
      if (!(nn == 15 && kt >= NT-2)){
        int g2 = nn*NT + kt + 2;
        STAGE_B(sbuf, nstart + g2/NT, g2 % NT);
      }
      asm volatile("" ::: "memory");         // pin stage before misc/epi VMEM

      // MFMA phase: B from LDS, A from registers
      #pragma unroll
      for (int kk = 0; kk < 2; ++kk){
        short8 b[4];
        #pragma unroll
        for (int fn = 0; fn < 4; ++fn){
          int r = wn*64 + fn*16 + lrow;
          int idx = (r*64 + kk*32 + lk*8) ^ ((r & 7) << 3);
          b[fn] = *(const short8*)(&lds[cbuf*16384 + idx]);
        }
        #pragma unroll
        for (int fm = 0; fm < 4; ++fm)
          #pragma unroll
          for (int fn = 0; fn < 4; ++fn)
            acc[fm][fn] = __builtin_amdgcn_mfma_f32_16x16x32_bf16(areg[kt][kk][fm], b[fn], acc[fm][fn], 0, 0, 0);
      }

      if (epi){
        // 12 misc VMEM loads (4x dwordx4 + 8x dword), then reduce + 4 stores
        const int gidx = LAYER*512 + n*4 + wn;   // wn == k
        float4 gv[4];
        float bbv[4], wsv[4];
        #pragma unroll
        for (int fm = 0; fm < 4; ++fm)
          gv[fm] = *(const float4*)(GT + (size_t)gidx*4096 + bbase + wm*64 + fm*16 + lk*4);
        #pragma unroll
        for (int fn = 0; fn < 4; ++fn){
          int c = wn*64 + fn*16 + lrow;
          bbv[fn] = bb[n*256 + c];
          wsv[fn] = Ws[n*256 + c];
        }
        #pragma unroll
        for (int fm = 0; fm < 4; ++fm){
          float gr[4] = {gv[fm].x, gv[fm].y, gv[fm].z, gv[fm].w};
          float sums[4];
          #pragma unroll
          for (int reg = 0; reg < 4; ++reg){
            float s = 0.f;
            #pragma unroll
            for (int fn = 0; fn < 4; ++fn)
              s += fmaxf(acc[fm][fn][reg] + bbv[fn], 0.f) * wsv[fn];
            s *= gr[reg];
            s += __shfl_xor(s, 1);
            s += __shfl_xor(s, 2);
            s += __shfl_xor(s, 4);
            s += __shfl_xor(s, 8);
            sums[reg] = s;
          }
          if (lrow == 0){
            float4 o; o.x = sums[0]; o.y = sums[1]; o.z = sums[2]; o.w = sums[3];
            *(float4*)(partg + (size_t)wn*524288 + (size_t)n*4096
                       + bbase + wm*64 + fm*16 + lk*4) = o;
          }
        }
        #pragma unroll
        for (int i2 = 0; i2 < 4; ++i2)
          #pragma unroll
          for (int j2 = 0; j2 < 4; ++j2) acc[i2][j2] = zero;
      }
      cbuf = (cbuf == 2) ? 0 : cbuf + 1;
      sbuf = (sbuf == 2) ? 0 : sbuf + 1;
    }
  }
}

// ---------- 6.5 partial fold: out[b][n] = sum_wn partg[wn][n][b] + bs[n] ----------
template<int OUT_BF>
__global__ void k_mid(const float* __restrict__ partg, const float* __restrict__ bsv,
                      unsigned short* __restrict__ obf, float* __restrict__ of32){
  const int n = blockIdx.x;          // 128
  const int t = threadIdx.x;         // 256 threads x 16 b each
  const float* p = partg + (size_t)n*4096 + t*16;
  const float bsn = bsv[n];
  #pragma unroll
  for (int i = 0; i < 4; ++i){
    float4 s0 = *(const float4*)(p + i*4);
    float4 s1 = *(const float4*)(p + 524288 + i*4);
    float4 s2 = *(const float4*)(p + 2*524288 + i*4);
    float4 s3 = *(const float4*)(p + 3*524288 + i*4);
    float v0 = ((s0.x + s1.x) + s2.x) + s3.x + bsn;
    float v1 = ((s0.y + s1.y) + s2.y) + s3.y + bsn;
    float v2 = ((s0.z + s1.z) + s2.z) + s3.z + bsn;
    float v3 = ((s0.w + s1.w) + s2.w) + s3.w + bsn;
    size_t b = (size_t)t*16 + i*4;
    if (OUT_BF){
      obf[(b+0)*128 + n] = f2bf(v0);
      obf[(b+1)*128 + n] = f2bf(v1);
      obf[(b+2)*128 + n] = f2bf(v2);
      obf[(b+3)*128 + n] = f2bf(v3);
    } else {
      of32[(b+0)*128 + n] = v0;
      of32[(b+1)*128 + n] = v1;
      of32[(b+2)*128 + n] = v2;
      of32[(b+3)*128 + n] = v3;
    }
  }
}

// ---------- 7. final projection: out = cur1 @ Wout.T + bout ----------
__global__ void k_final(const float* __restrict__ out1, const float* __restrict__ Wout,
                        const float* __restrict__ bout, float* __restrict__ out){
  int t = blockIdx.x*256 + threadIdx.x;
  int b = t >> 7, o = t & 127;
  const float4* cr = (const float4*)(out1 + (size_t)b*128);
  const float4* wr = (const float4*)(Wout + (size_t)o*128);
  float a = 0.f;
  #pragma unroll
  for (int i = 0; i < 32; ++i){
    float4 c = cr[i], w = wr[i];
    a += c.x*w.x + c.y*w.y + c.z*w.z + c.w*w.w;
  }
  out[t] = a + bout[o];
}

// ---------- launch ----------
extern "C" void kernel_launch(void* const* d_in, const int* in_sizes, int n_in,
                              void* d_out, int out_size, void* d_ws, size_t ws_size,
                              hipStream_t stream){
  const float* x    = (const float*)d_in[0];
  const float* ctx  = (const float*)d_in[1];
  const float* Wb0  = (const float*)d_in[2];
  const float* bb0  = (const float*)d_in[3];
  const float* Ws0  = (const float*)d_in[4];
  const float* bs0  = (const float*)d_in[5];
  const float* Wb1  = (const float*)d_in[6];
  const float* bb1  = (const float*)d_in[7];
  const float* Ws1  = (const float*)d_in[8];
  const float* bs1  = (const float*)d_in[9];
  const float* Wout = (const float*)d_in[10];
  const float* bout = (const float*)d_in[11];
  const float* h1w  = (const float*)d_in[12];
  const float* h1b  = (const float*)d_in[13];
  const float* h2w  = (const float*)d_in[14];
  const float* h2b  = (const float*)d_in[15];
  const float* h3w  = (const float*)d_in[16];
  const float* h3b  = (const float*)d_in[17];
  float* out = (float*)d_out;

  char* ws = (char*)d_ws;
  size_t o = 0;
  unsigned short* x_bf  = (unsigned short*)(ws + o); o += (size_t)4096*256*2;
  unsigned short* W0b   = (unsigned short*)(ws + o); o += (size_t)8388608*2;
  unsigned short* W1b   = (unsigned short*)(ws + o); o += (size_t)4194304*2;
  unsigned short* Wg_bf = (unsigned short*)(ws + o); o += (size_t)1024*256*2;
  float* bg   = (float*)(ws + o); o += 1024*4;
  float* hv2  = (float*)(ws + o); o += 256;
  float* GT   = (float*)(ws + o); o += (size_t)1024*4096*4;
  unsigned short* cur_bf = (unsigned short*)(ws + o); o += (size_t)4096*128*2;
  float* out1 = (float*)(ws + o); o += (size_t)4096*128*4;
  float* partg0 = (float*)(ws + o); o += (size_t)4*128*4096*4;   // 8 MB
  float* partg1 = (float*)W0b;      // alias: W0b dead after k_layer0

  k_convert<<<13312, 256, 0, stream>>>(x, Wb0, Wb1, x_bf, W0b, W1b);
  k_hyper<<<1, 64, 0, stream>>>(ctx, h1w, h1b, h2w, h2b, hv2);
  k_gw<<<4112, 256, 0, stream>>>(hv2, h3w, h3b, Wg_bf, bg);
  k_gates<<<dim3(8, 16), 512, 0, stream>>>(Wg_bf, x_bf, bg, GT);
  k_layer<256, 0><<<256, 512, 0, stream>>>(x_bf, W0b, bb0, Ws0, GT, partg0);
  k_mid<1><<<128, 256, 0, stream>>>(partg0, bs0, cur_bf, nullptr);
  k_layer<128, 1><<<256, 512, 0, stream>>>(cur_bf, W1b, bb1, Ws1, GT, partg1);
  k_mid<0><<<128, 256, 0, stream>>>(partg1, bs1, nullptr, out1);
  k_final<<<2048, 256, 0, stream>>>(out1, Wout, bout, out);
}

// Round 8
// 226.602 us; speedup vs baseline: 1.0908x; 1.0908x over previous
//
#include <hip/hip_runtime.h>

// ---------- problem constants ----------
#define BB   4096   // batch
#define IN_  256
#define NN   128
#define KK   4
#define JJ   64
#define NG   512        // N*K
#define WS_  131072     // IN*NG
#define PER  131584     // WS_+NG
#define TP   263168     // 2*PER
#define OUTD 128

typedef __attribute__((ext_vector_type(8))) short short8;
typedef __attribute__((ext_vector_type(4))) float f32x4;

#define VW(N) asm volatile("s_waitcnt vmcnt(" #N ")" ::: "memory")

__device__ __forceinline__ unsigned short f2bf(float f){
  unsigned u = __float_as_uint(f);
  return (unsigned short)((u + 0x7fffu + ((u >> 16) & 1u)) >> 16);
}

__device__ __forceinline__ void gload16(const void* g, void* l){
  __builtin_amdgcn_global_load_lds((const __attribute__((address_space(1))) void*)g,
                                   (__attribute__((address_space(3))) void*)l, 16, 0, 0);
}

// ---------- 1. f32 -> bf16 convert: x, Wb0, Wb1 ----------
#define XE  (4096u*256u)            // 1048576
#define W0E (XE + 8388608u)         // + 128*4*64*256
#define W1E (W0E + 4194304u)        // + 128*4*64*128

__global__ void k_convert(const float* __restrict__ x,
                          const float* __restrict__ w0,
                          const float* __restrict__ w1,
                          unsigned short* __restrict__ xb,
                          unsigned short* __restrict__ w0b,
                          unsigned short* __restrict__ w1b){
  size_t i = ((size_t)blockIdx.x*256 + threadIdx.x)*4;
  if (i >= W1E) return;
  const float* s; unsigned short* d; size_t off;
  if (i < XE)       { s = x;  d = xb;  off = i; }
  else if (i < W0E) { s = w0; d = w0b; off = i - XE; }
  else              { s = w1; d = w1b; off = i - W0E; }
  float4 v = *(const float4*)(s + off);
  ushort4 o;
  o.x = f2bf(v.x); o.y = f2bf(v.y); o.z = f2bf(v.z); o.w = f2bf(v.w);
  *(ushort4*)(d + off) = o;
}

// ---------- 2. hypernet MLP (context -> hv2[64]) ----------
__global__ void k_hyper(const float* __restrict__ ctx,
                        const float* __restrict__ h1w, const float* __restrict__ h1b,
                        const float* __restrict__ h2w, const float* __restrict__ h2b,
                        float* __restrict__ hv2){
  __shared__ float s1[32];
  int t = threadIdx.x;
  if (t < 32){
    float a = h1b[t];
    #pragma unroll 8
    for (int i = 0; i < 64; ++i) a += ctx[i]*h1w[t*64+i];
    s1[t] = fmaxf(a, 0.f);
  }
  __syncthreads();
  float a = h2b[t];
  #pragma unroll 8
  for (int i = 0; i < 32; ++i) a += s1[i]*h2w[t*32+i];
  hv2[t] = fmaxf(a, 0.f);
}

// ---------- 3. gw = hv2 @ h3w.T + h3b  ->  Wg_bf (1024x256 bf16), bg (1024 f32) ----------
__global__ void k_gw(const float* __restrict__ hv2,
                     const float* __restrict__ h3w, const float* __restrict__ h3b,
                     unsigned short* __restrict__ Wg_bf, float* __restrict__ bg){
  int t = threadIdx.x;
  int r = blockIdx.x*64 + (t >> 2);
  int q = t & 3;
  const float4* row = (const float4*)(h3w + (size_t)r*64);
  float a = 0.f;
  #pragma unroll
  for (int i = 0; i < 4; ++i){
    float4 v = row[q*4 + i];
    float4 h = *(const float4*)(hv2 + q*16 + i*4);
    a += v.x*h.x + v.y*h.y + v.z*h.z + v.w*h.w;
  }
  a += __shfl_xor(a, 1);
  a += __shfl_xor(a, 2);
  if (q == 0){
    a += h3b[r];
    if (r < WS_)          Wg_bf[r] = f2bf(a);
    else if (r < PER)     bg[r - WS_] = a;
    else if (r < PER+WS_) Wg_bf[WS_ + (r - PER)] = f2bf(a);
    else                  bg[512 + (r - (PER+WS_))] = a;
  }
}

// ---------- 4. gates GEMM: G_T[m(1024)][b(4096)] = sigmoid(Wg[m]·x[b] + bg[m]) ----------
__global__ __launch_bounds__(512, 1)
void k_gates(const unsigned short* __restrict__ Wg_bf,  // 1024 x 256
             const unsigned short* __restrict__ x_bf,   // 4096 x 256
             const float* __restrict__ bg,              // 1024
             float* __restrict__ GT){                    // 1024 x 4096
  __shared__ __align__(16) unsigned short As[128*64];
  __shared__ __align__(16) unsigned short Bs[256*64];
  const int tid  = threadIdx.x;
  const int lane = tid & 63;
  const int wid  = tid >> 6;
  const int wm = wid >> 2, wn = wid & 3;
  const int lrow = lane & 15, lk = lane >> 4;
  const int m0 = blockIdx.x*128;
  const int b0 = blockIdx.y*256;

  f32x4 zero = {0.f,0.f,0.f,0.f};
  f32x4 acc[4][4];
  #pragma unroll
  for (int i=0;i<4;++i)
    #pragma unroll
    for (int j=0;j<4;++j) acc[i][j] = zero;

  for (int kt = 0; kt < 256/64; ++kt){
    __syncthreads();
    #pragma unroll
    for (int i = 0; i < 2; ++i){
      int c = tid + i*512;
      int row = c >> 3, k8 = c & 7;
      uint4 v = *(const uint4*)(Wg_bf + (size_t)(m0+row)*256 + kt*64 + k8*8);
      int idx = (row*64 + k8*8) ^ ((row & 7) << 3);
      *(uint4*)(&As[idx]) = v;
    }
    #pragma unroll
    for (int i = 0; i < 4; ++i){
      int c = tid + i*512;
      int row = c >> 3, k8 = c & 7;
      uint4 v = *(const uint4*)(x_bf + (size_t)(b0+row)*256 + kt*64 + k8*8);
      int idx = (row*64 + k8*8) ^ ((row & 7) << 3);
      *(uint4*)(&Bs[idx]) = v;
    }
    __syncthreads();
    #pragma unroll
    for (int kk = 0; kk < 2; ++kk){
      short8 a[4], b[4];
      #pragma unroll
      for (int fm = 0; fm < 4; ++fm){
        int m = wm*64 + fm*16 + lrow;
        int idx = (m*64 + kk*32 + lk*8) ^ ((m & 7) << 3);
        a[fm] = *(const short8*)(&As[idx]);
      }
      #pragma unroll
      for (int fn = 0; fn < 4; ++fn){
        int r = wn*64 + fn*16 + lrow;
        int idx = (r*64 + kk*32 + lk*8) ^ ((r & 7) << 3);
        b[fn] = *(const short8*)(&Bs[idx]);
      }
      #pragma unroll
      for (int fm = 0; fm < 4; ++fm)
        #pragma unroll
        for (int fn = 0; fn < 4; ++fn)
          acc[fm][fn] = __builtin_amdgcn_mfma_f32_16x16x32_bf16(a[fm], b[fn], acc[fm][fn], 0, 0, 0);
    }
  }
  #pragma unroll
  for (int fm = 0; fm < 4; ++fm){
    float4 bgv = *(const float4*)(bg + m0 + wm*64 + fm*16 + lk*4);
    float bga[4] = {bgv.x, bgv.y, bgv.z, bgv.w};
    #pragma unroll
    for (int reg = 0; reg < 4; ++reg){
      int m = m0 + wm*64 + fm*16 + lk*4 + reg;
      #pragma unroll
      for (int fn = 0; fn < 4; ++fn){
        int b = b0 + wn*64 + fn*16 + lrow;
        float z = acc[fm][fn][reg] + bga[reg];
        GT[(size_t)m*4096 + b] = 1.f/(1.f + __expf(-z));
      }
    }
  }
}

// ---------- 5/6. fused DANN layer (Wb-resident, x-streaming) ----------
// Block = layer0: (n, khalf) -> Wb slice [128 cols][256 K] = 64 KB resident.
//         layer1: (n, bhalf) -> Wb [256 cols][128 K] = 64 KB resident.
// x/cur streams through a 2-buf A-tile (32/16 KB per kt-phase); x is 1-2 MB,
// L2-resident on every XCD -> staging latency is L2-class and hidden by the
// ~1300-cyc phase. bb/Ws hoisted (block constants). Gates prefetched at kt=0,
// used at kt=NT-1. Epilogue barrier-free (partg + k_mid, as round 6).
// Per-wave VMEM per phase: S=AI stage ops (+G=4 gates at kt0, +E=4 stores at
// epi). Issue order [drain, barrier, S, G?, ds/MFMA, E?] gives exact drains:
//   ph==0 -> VW(0) (prologue); kt==0 -> VW(4) (E younger); kt==1 -> VW(4)
//   (G younger); kt>=2 -> VW(0).
template<int KIN, int LAYER>
__global__ __launch_bounds__(512, 1)
void k_layer(const unsigned short* __restrict__ Abf,  // (4096, KIN) bf16
             const unsigned short* __restrict__ Wbf,  // (32768, KIN) bf16
             const float* __restrict__ bb,            // 32768
             const float* __restrict__ Ws,            // 128*256
             const float* __restrict__ GT,            // 1024 x 4096
             float* __restrict__ partg){              // [4][128][4096] f32
  constexpr int NT     = KIN/64;                 // 4 / 2
  constexpr int SC     = (LAYER==0) ? 128 : 256; // resident Wb cols
  constexpr int WN     = (LAYER==0) ? 2 : 4;     // waves across cols
  constexpr int WMN    = 8/WN;                   // waves across rows
  constexpr int BTR    = WMN*64;                 // b-tile rows: 256 / 128
  constexpr int NBT    = 16;                     // b-tiles per block
  constexpr int ABUFSZ = BTR*64;                 // shorts per A buf
  constexpr int WBOFF  = 2*ABUFSZ;               // shorts
  constexpr int AI     = BTR/64;                 // stage-A instrs/wave: 4 / 2
  constexpr int WI     = SC/64;                  // stage-W instrs/wave/kt: 2 / 4
  __shared__ __align__(16) unsigned short lds[WBOFF + SC*64*NT];

  const int tid  = threadIdx.x;
  const int lane = tid & 63;
  const int wid  = tid >> 6;
  const int wn   = wid % WN, wm = wid / WN;
  const int lrow = lane & 15, lk = lane >> 4;

  const int id      = blockIdx.x;                // 0..255
  const int n       = id >> 1;
  const int sub     = id & 1;                    // khalf (L0) / bhalf (L1)
  const int kgrp    = (LAYER==0) ? sub*2 + wn : wn;
  const int abase   = (LAYER==0) ? 0 : sub*2048; // b-range base
  const int colbase = n*256 + ((LAYER==0) ? sub*128 : 0); // global Wb row

  f32x4 zero = {0.f,0.f,0.f,0.f};
  f32x4 acc[4][4];
  #pragma unroll
  for (int i=0;i<4;++i)
    #pragma unroll
    for (int jj=0;jj<4;++jj) acc[i][jj] = zero;

  // A-tile stage: BTR x 64, linear LDS dest, pre-swizzled global src
  auto STAGE_A = [&](int buf, int bt, int kt){
    #pragma unroll
    for (int i = 0; i < AI; ++i){
      int c = i*512 + tid;
      int r = c >> 3, kc = c & 7;
      const unsigned short* s = Abf + (size_t)(abase + bt*BTR + r)*KIN + kt*64 + ((kc ^ (r&7))<<3);
      gload16(s, &lds[buf*ABUFSZ + (i*512 + wid*64)*8]);
    }
  };

  // prologue: resident Wb slice (all kt) + A tile for phase 0
  #pragma unroll
  for (int kt = 0; kt < NT; ++kt)
    #pragma unroll
    for (int i = 0; i < WI; ++i){
      int c = i*512 + tid;
      int r = c >> 3, kc = c & 7;
      const unsigned short* s = Wbf + (size_t)(colbase + r)*KIN + kt*64 + ((kc ^ (r&7))<<3);
      gload16(s, &lds[WBOFF + kt*SC*64 + (i*512 + wid*64)*8]);
    }
  STAGE_A(0, 0, 0);
  asm volatile("" ::: "memory");

  // block-constant epilogue params (hoisted out of the loop)
  float bbv[4], wsv[4];
  #pragma unroll
  for (int fn = 0; fn < 4; ++fn){
    int cloc = ((LAYER==0) ? sub*128 : 0) + wn*64 + fn*16 + lrow;
    bbv[fn] = bb[n*256 + cloc];
    wsv[fn] = Ws[n*256 + cloc];
  }
  const float* gtrow = GT + (size_t)(LAYER*512 + n*4 + kgrp)*4096 + abase;
  float* prow = partg + (size_t)kgrp*524288 + (size_t)n*4096 + abase;

  int abuf = 0;
  #pragma unroll 1
  for (int bt = 0; bt < NBT; ++bt){
    float4 gv[4];
    #pragma unroll
    for (int kt = 0; kt < NT; ++kt){
      const int  ph  = bt*NT + kt;
      const bool epi = (kt == NT-1);

      // drain stage(ph): exact counted vmcnt per header comment
      if (ph == 0)      VW(0);
      else if (kt <= 1) VW(4);
      else              VW(0);
      __builtin_amdgcn_s_barrier();            // publish A buf for this phase

      // stage next phase's A tile (buffer safe: all waves crossed barrier)
      if (ph + 1 < NBT*NT){
        int bt2 = epi ? bt+1 : bt;
        int kt2 = epi ? 0    : kt+1;
        STAGE_A(abuf ^ 1, bt2, kt2);
      }
      asm volatile("" ::: "memory");           // pin: S before G

      if (kt == 0){                            // prefetch gates for this bt
        #pragma unroll
        for (int fm = 0; fm < 4; ++fm)
          gv[fm] = *(const float4*)(gtrow + bt*BTR + wm*64 + fm*16 + lk*4);
        asm volatile("" ::: "memory");         // pin: G before ds/MFMA
      }

      // MFMA phase: A from abuf, B from resident Wb[kt]
      #pragma unroll
      for (int kk = 0; kk < 2; ++kk){
        short8 a[4], b[4];
        #pragma unroll
        for (int fm = 0; fm < 4; ++fm){
          int m = wm*64 + fm*16 + lrow;
          int idx = abuf*ABUFSZ + ((m*64 + kk*32 + lk*8) ^ ((m & 7) << 3));
          a[fm] = *(const short8*)(&lds[idx]);
        }
        #pragma unroll
        for (int fn = 0; fn < 4; ++fn){
          int r = wn*64 + fn*16 + lrow;
          int idx = WBOFF + kt*SC*64 + ((r*64 + kk*32 + lk*8) ^ ((r & 7) << 3));
          b[fn] = *(const short8*)(&lds[idx]);
        }
        #pragma unroll
        for (int fm = 0; fm < 4; ++fm)
          #pragma unroll
          for (int fn = 0; fn < 4; ++fn)
            acc[fm][fn] = __builtin_amdgcn_mfma_f32_16x16x32_bf16(a[fm], b[fn], acc[fm][fn], 0, 0, 0);
      }

      if (epi){
        // relu(+bb)*Ws, gate, 16-lane shuffle reduce, 4 float4 stores. No sync.
        #pragma unroll
        for (int fm = 0; fm < 4; ++fm){
          float gr[4] = {gv[fm].x, gv[fm].y, gv[fm].z, gv[fm].w};
          float sums[4];
          #pragma unroll
          for (int reg = 0; reg < 4; ++reg){
            float s = 0.f;
            #pragma unroll
            for (int fn = 0; fn < 4; ++fn)
              s += fmaxf(acc[fm][fn][reg] + bbv[fn], 0.f) * wsv[fn];
            s *= gr[reg];
            s += __shfl_xor(s, 1);
            s += __shfl_xor(s, 2);
            s += __shfl_xor(s, 4);
            s += __shfl_xor(s, 8);
            sums[reg] = s;
          }
          if (lrow == 0){
            float4 o; o.x = sums[0]; o.y = sums[1]; o.z = sums[2]; o.w = sums[3];
            *(float4*)(prow + bt*BTR + wm*64 + fm*16 + lk*4) = o;
          }
        }
        #pragma unroll
        for (int i2 = 0; i2 < 4; ++i2)
          #pragma unroll
          for (int j2 = 0; j2 < 4; ++j2) acc[i2][j2] = zero;
      }
      abuf ^= 1;
    }
  }
}

// ---------- 6.5 partial fold: out[b][n] = sum_wn partg[wn][n][b] + bs[n] ----------
template<int OUT_BF>
__global__ void k_mid(const float* __restrict__ partg, const float* __restrict__ bsv,
                      unsigned short* __restrict__ obf, float* __restrict__ of32){
  const int n = blockIdx.x;          // 128
  const int t = threadIdx.x;         // 256 threads x 16 b each
  const float* p = partg + (size_t)n*4096 + t*16;
  const float bsn = bsv[n];
  #pragma unroll
  for (int i = 0; i < 4; ++i){
    float4 s0 = *(const float4*)(p + i*4);
    float4 s1 = *(const float4*)(p + 524288 + i*4);
    float4 s2 = *(const float4*)(p + 2*524288 + i*4);
    float4 s3 = *(const float4*)(p + 3*524288 + i*4);
    float v0 = ((s0.x + s1.x) + s2.x) + s3.x + bsn;
    float v1 = ((s0.y + s1.y) + s2.y) + s3.y + bsn;
    float v2 = ((s0.z + s1.z) + s2.z) + s3.z + bsn;
    float v3 = ((s0.w + s1.w) + s2.w) + s3.w + bsn;
    size_t b = (size_t)t*16 + i*4;
    if (OUT_BF){
      obf[(b+0)*128 + n] = f2bf(v0);
      obf[(b+1)*128 + n] = f2bf(v1);
      obf[(b+2)*128 + n] = f2bf(v2);
      obf[(b+3)*128 + n] = f2bf(v3);
    } else {
      of32[(b+0)*128 + n] = v0;
      of32[(b+1)*128 + n] = v1;
      of32[(b+2)*128 + n] = v2;
      of32[(b+3)*128 + n] = v3;
    }
  }
}

// ---------- 7. final projection: out = cur1 @ Wout.T + bout ----------
__global__ void k_final(const float* __restrict__ out1, const float* __restrict__ Wout,
                        const float* __restrict__ bout, float* __restrict__ out){
  int t = blockIdx.x*256 + threadIdx.x;
  int b = t >> 7, o = t & 127;
  const float4* cr = (const float4*)(out1 + (size_t)b*128);
  const float4* wr = (const float4*)(Wout + (size_t)o*128);
  float a = 0.f;
  #pragma unroll
  for (int i = 0; i < 32; ++i){
    float4 c = cr[i], w = wr[i];
    a += c.x*w.x + c.y*w.y + c.z*w.z + c.w*w.w;
  }
  out[t] = a + bout[o];
}

// ---------- launch ----------
extern "C" void kernel_launch(void* const* d_in, const int* in_sizes, int n_in,
                              void* d_out, int out_size, void* d_ws, size_t ws_size,
                              hipStream_t stream){
  const float* x    = (const float*)d_in[0];
  const float* ctx  = (const float*)d_in[1];
  const float* Wb0  = (const float*)d_in[2];
  const float* bb0  = (const float*)d_in[3];
  const float* Ws0  = (const float*)d_in[4];
  const float* bs0  = (const float*)d_in[5];
  const float* Wb1  = (const float*)d_in[6];
  const float* bb1  = (const float*)d_in[7];
  const float* Ws1  = (const float*)d_in[8];
  const float* bs1  = (const float*)d_in[9];
  const float* Wout = (const float*)d_in[10];
  const float* bout = (const float*)d_in[11];
  const float* h1w  = (const float*)d_in[12];
  const float* h1b  = (const float*)d_in[13];
  const float* h2w  = (const float*)d_in[14];
  const float* h2b  = (const float*)d_in[15];
  const float* h3w  = (const float*)d_in[16];
  const float* h3b  = (const float*)d_in[17];
  float* out = (float*)d_out;

  char* ws = (char*)d_ws;
  size_t o = 0;
  unsigned short* x_bf  = (unsigned short*)(ws + o); o += (size_t)4096*256*2;
  unsigned short* W0b   = (unsigned short*)(ws + o); o += (size_t)8388608*2;
  unsigned short* W1b   = (unsigned short*)(ws + o); o += (size_t)4194304*2;
  unsigned short* Wg_bf = (unsigned short*)(ws + o); o += (size_t)1024*256*2;
  float* bg   = (float*)(ws + o); o += 1024*4;
  float* hv2  = (float*)(ws + o); o += 256;
  float* GT   = (float*)(ws + o); o += (size_t)1024*4096*4;
  unsigned short* cur_bf = (unsigned short*)(ws + o); o += (size_t)4096*128*2;
  float* out1 = (float*)(ws + o); o += (size_t)4096*128*4;
  float* partg0 = (float*)(ws + o); o += (size_t)4*128*4096*4;   // 8 MB
  float* partg1 = (float*)W0b;      // alias: W0b dead after k_layer0

  k_convert<<<13312, 256, 0, stream>>>(x, Wb0, Wb1, x_bf, W0b, W1b);
  k_hyper<<<1, 64, 0, stream>>>(ctx, h1w, h1b, h2w, h2b, hv2);
  k_gw<<<4112, 256, 0, stream>>>(hv2, h3w, h3b, Wg_bf, bg);
  k_gates<<<dim3(8, 16), 512, 0, stream>>>(Wg_bf, x_bf, bg, GT);
  k_layer<256, 0><<<256, 512, 0, stream>>>(x_bf, W0b, bb0, Ws0, GT, partg0);
  k_mid<1><<<128, 256, 0, stream>>>(partg0, bs0, cur_bf, nullptr);
  k_layer<128, 1><<<256, 512, 0, stream>>>(cur_bf, W1b, bb1, Ws1, GT, partg1);
  k_mid<0><<<128, 256, 0, stream>>>(partg1, bs1, nullptr, out1);
  k_final<<<2048, 256, 0, stream>>>(out1, Wout, bout, out);
}